// Round 2
// baseline (1185.491 us; speedup 1.0000x reference)
//
#include <hip/hip_runtime.h>
#include <cstdio>
#include <cstdint>

typedef __bf16 bf16;
typedef __bf16 bf16x8 __attribute__((ext_vector_type(8)));
typedef __bf16 bf16x4 __attribute__((ext_vector_type(4)));
typedef float  f32x4  __attribute__((ext_vector_type(4)));

#define SEQ  2048
#define DIMM 2048
#define ROWS 4096   // B*S
#define EPSF 1e-5f

// ---- async global->LDS, 16B per lane (dest must be waveuniform + lane*16) ----
__device__ __forceinline__ void g2l16(const void* g, void* l) {
  __builtin_amdgcn_global_load_lds((__attribute__((address_space(1))) void*)g,
                                   (__attribute__((address_space(3))) void*)l,
                                   16, 0, 0);
}

// ============================================================================
// GEMM: C[M,N] = A[M,K] @ Bw[N,K]^T (+bias, + mode-specific epilogue)
// 128x128 tile, BK=32, 256 threads = 4 waves (2x2 of 64x64), 16x16x32 bf16 MFMA
// MODE 0: bf16 out = acc + bias0
// MODE 1: f32 out  = resid + acc + bias0          (in-place on resid allowed)
// MODE 3: f32 out  = acc + bias0
// MODE 4: f32 out  = resid + silu(g1) * (acc + bias0)
// MODE 5: bf16 out, tri-bias (QKV fused: col<2048 bq, <4096 bk, else bv)
// ============================================================================
template<int MODE>
__global__ __launch_bounds__(256)
void gemm_bt(const bf16* __restrict__ A, int ldA,
             const bf16* __restrict__ Bw, int K,
             const float* __restrict__ bias0,
             const float* __restrict__ bias1,
             const float* __restrict__ bias2,
             void* Cout, int ldC,
             const float* resid,
             const float* g1)
{
  __shared__ bf16 sA[128 * 32];
  __shared__ bf16 sB[128 * 32];
  const int tid  = threadIdx.x;
  const int lane = tid & 63;
  const int wave = tid >> 6;
  const int wm = wave >> 1, wn = wave & 1;
  const long row0 = (long)blockIdx.y * 128;
  const long col0 = (long)blockIdx.x * 128;

  const bf16* Ab = A  + row0 * ldA;
  const bf16* Bb = Bw + col0 * (long)K;

  f32x4 acc[4][4] = {};

  // staging chunk ids: 512 x 16B chunks per tile, 2 per thread
  const int c0 = tid,        c1 = tid + 256;
  const int r0 = c0 >> 2,    cc0 = (c0 & 3) * 8;
  const int r1 = c1 >> 2,    cc1 = (c1 & 3) * 8;

  for (int k0 = 0; k0 < K; k0 += 32) {
    g2l16(Ab + (long)r0 * ldA + k0 + cc0, sA + c0 * 8);
    g2l16(Ab + (long)r1 * ldA + k0 + cc1, sA + c1 * 8);
    g2l16(Bb + (long)r0 * K   + k0 + cc0, sB + c0 * 8);
    g2l16(Bb + (long)r1 * K   + k0 + cc1, sB + c1 * 8);
    __syncthreads();   // also drains vmcnt for global_load_lds
    const int lm = lane & 15, lq = lane >> 4;
    bf16x8 af[4], bfr[4];
#pragma unroll
    for (int mi = 0; mi < 4; ++mi)
      af[mi] = *(const bf16x8*)(sA + (wm * 64 + mi * 16 + lm) * 32 + lq * 8);
#pragma unroll
    for (int ni = 0; ni < 4; ++ni)
      bfr[ni] = *(const bf16x8*)(sB + (wn * 64 + ni * 16 + lm) * 32 + lq * 8);
#pragma unroll
    for (int mi = 0; mi < 4; ++mi)
#pragma unroll
      for (int ni = 0; ni < 4; ++ni)
        acc[mi][ni] = __builtin_amdgcn_mfma_f32_16x16x32_bf16(af[mi], bfr[ni], acc[mi][ni], 0, 0, 0);
    __syncthreads();
  }

  // epilogue: C/D layout col=lane&15, row=(lane>>4)*4+reg  [m89/m91 verified]
  const int lm = lane & 15, lq = lane >> 4;
#pragma unroll
  for (int ni = 0; ni < 4; ++ni) {
    const long col = col0 + wn * 64 + ni * 16 + lm;
    float bv;
    if (MODE == 5)
      bv = (col < 2048) ? bias0[col] : (col < 4096 ? bias1[col - 2048] : bias2[col - 4096]);
    else
      bv = bias0[col];
#pragma unroll
    for (int mi = 0; mi < 4; ++mi) {
#pragma unroll
      for (int r = 0; r < 4; ++r) {
        const long row = row0 + wm * 64 + mi * 16 + lq * 4 + r;
        const long idx = row * ldC + col;
        const float v = acc[mi][ni][r] + bv;
        if (MODE == 0 || MODE == 5) {
          ((bf16*)Cout)[idx] = (bf16)v;
        } else if (MODE == 1) {
          ((float*)Cout)[idx] = resid[idx] + v;
        } else if (MODE == 3) {
          ((float*)Cout)[idx] = v;
        } else { // MODE 4
          const float g  = g1[idx];
          const float si = g / (1.f + __expf(-g));
          ((float*)Cout)[idx] = resid[idx] + si * v;
        }
      }
    }
  }
}

// ============================================================================
// fused (optional additive-rotary) + RMSNorm: h = scale * x / sqrt(sum(x^2)+eps)
// one block per row; optionally writes fp32 x(+rot) residual
// ============================================================================
__global__ __launch_bounds__(256)
void rms_rot(const float* __restrict__ xin,
             const float* __restrict__ scale,
             float* __restrict__ xr_out,
             bf16* __restrict__ h_out,
             int do_rot)
{
  const int row = blockIdx.x, tid = threadIdx.x;
  const float s = (float)(row & (SEQ - 1));
  const float4* xrow = (const float4*)(xin + (long)row * DIMM);
  float4 v[2];
  float ss = 0.f;
#pragma unroll
  for (int i = 0; i < 2; ++i) {
    const int j4 = tid + i * 256;
    float4 xv = xrow[j4];
    if (do_rot) {
      float* xp = (float*)&xv;
#pragma unroll
      for (int l = 0; l < 4; ++l) {
        const int idx = (j4 * 4 + l) & 1023;   // table[j] = s * 10000^(-(j&1023)/1024)
        xp[l] += s * exp2f((float)idx * -0.0129762816206537569f); // -log2(1e4)/1024
      }
    }
    v[i] = xv;
    ss += xv.x * xv.x + xv.y * xv.y + xv.z * xv.z + xv.w * xv.w;
    if (xr_out) ((float4*)(xr_out + (long)row * DIMM))[j4] = xv;
  }
#pragma unroll
  for (int off = 32; off > 0; off >>= 1) ss += __shfl_down(ss, off, 64);
  __shared__ float red[4];
  if ((tid & 63) == 0) red[tid >> 6] = ss;
  __syncthreads();
  const float rn = rsqrtf(red[0] + red[1] + red[2] + red[3] + EPSF);
  bf16* hrow = h_out + (long)row * DIMM;
#pragma unroll
  for (int i = 0; i < 2; ++i) {
    const int j4 = tid + i * 256;
    const float4 xv = v[i];
    const float4 s4 = ((const float4*)scale)[j4];
    bf16x4 o;
    o[0] = (bf16)(s4.x * xv.x * rn);
    o[1] = (bf16)(s4.y * xv.y * rn);
    o[2] = (bf16)(s4.z * xv.z * rn);
    o[3] = (bf16)(s4.w * xv.w * rn);
    *(bf16x4*)(hrow + j4 * 4) = o;
  }
}

// ============================================================================
// per-position attention over HEADS (the reference's einsum): one block per
// token position. scores[q,k] = dot64(Qh[q],Kh[k])/8, softmax over k (32),
// ctx[q,:] = attn @ Vh. Reads QKV row [6144], writes ctx into the Q slot.
// LDS padded (stride 68 / 33) to avoid stride-64 bank conflicts.
// ============================================================================
__global__ __launch_bounds__(256)
void attn_kernel(const bf16* QKV, bf16* CTX)
{
  __shared__ float qs[32 * 68];
  __shared__ float ks[32 * 68];
  __shared__ float vs[2048];
  __shared__ float sc[32 * 33];
  const int p = blockIdx.x, tid = threadIdx.x;
  const bf16* base = QKV + (long)p * 6144;
  {
    const bf16x8 q8 = *(const bf16x8*)(base + tid * 8);
    const bf16x8 k8 = *(const bf16x8*)(base + 2048 + tid * 8);
    const bf16x8 v8 = *(const bf16x8*)(base + 4096 + tid * 8);
    const int hi = tid >> 3, d0 = (tid & 7) * 8;
#pragma unroll
    for (int l = 0; l < 8; ++l) {
      qs[hi * 68 + d0 + l] = (float)q8[l];
      ks[hi * 68 + d0 + l] = (float)k8[l];
      vs[hi * 64 + d0 + l] = (float)v8[l];
    }
  }
  __syncthreads();
  { // scores: thread -> row qi = tid>>3, cols ki = (tid&7) + 8c
    const int qi = tid >> 3, ku = tid & 7;
    float a[4] = {0.f, 0.f, 0.f, 0.f};
#pragma unroll
    for (int d = 0; d < 64; d += 4) {
      const float4 qv = *(const float4*)&qs[qi * 68 + d];
#pragma unroll
      for (int c = 0; c < 4; ++c) {
        const float4 kv = *(const float4*)&ks[(ku + 8 * c) * 68 + d];
        a[c] += qv.x * kv.x + qv.y * kv.y + qv.z * kv.z + qv.w * kv.w;
      }
    }
#pragma unroll
    for (int c = 0; c < 4; ++c) sc[qi * 33 + ku + 8 * c] = a[c] * 0.125f;
  }
  __syncthreads();
  if (tid < 32) { // softmax per q-row over 32 kv heads
    float mx = -1e30f;
#pragma unroll
    for (int k = 0; k < 32; ++k) mx = fmaxf(mx, sc[tid * 33 + k]);
    float e[32], sum = 0.f;
#pragma unroll
    for (int k = 0; k < 32; ++k) { e[k] = __expf(sc[tid * 33 + k] - mx); sum += e[k]; }
    const float inv = 1.f / sum;
#pragma unroll
    for (int k = 0; k < 32; ++k) sc[tid * 33 + k] = e[k] * inv;
  }
  __syncthreads();
  { // ctx: thread -> q = tid>>3, d = (tid&7)*8 .. +7 ; coalesced 16B store
    const int q = tid >> 3, d0 = (tid & 7) * 8;
    float a[8] = {};
#pragma unroll
    for (int k = 0; k < 32; ++k) {
      const float w = sc[q * 33 + k];
      const float4 v0 = *(const float4*)&vs[k * 64 + d0];
      const float4 v1 = *(const float4*)&vs[k * 64 + d0 + 4];
      a[0] += w * v0.x; a[1] += w * v0.y; a[2] += w * v0.z; a[3] += w * v0.w;
      a[4] += w * v1.x; a[5] += w * v1.y; a[6] += w * v1.z; a[7] += w * v1.w;
    }
    bf16x8 o;
#pragma unroll
    for (int l = 0; l < 8; ++l) o[l] = (bf16)a[l];
    *(bf16x8*)(CTX + (long)p * 6144 + tid * 8) = o;
  }
}

// ============================================================================
// fp32 -> bf16 weight pool: [wq|wk|wv|wo|w_in|w1|w2]  (67,108,864 elements)
// ============================================================================
__global__ __launch_bounds__(256)
void convert_weights(const float* __restrict__ wq, const float* __restrict__ wk,
                     const float* __restrict__ wv, const float* __restrict__ wo,
                     const float* __restrict__ w_in, const float* __restrict__ w1,
                     const float* __restrict__ w2, bf16* __restrict__ dst)
{
  const long i = ((long)blockIdx.x * 256 + threadIdx.x) * 4;
  const float* src; long loc;
  if (i < (1L << 24)) {                 // 4 attn weights, 2^22 elems each
    const long seg = i >> 22;
    src = seg == 0 ? wq : seg == 1 ? wk : seg == 2 ? wv : wo;
    loc = i & ((1L << 22) - 1);
  } else {                              // 3 mlp weights, 2^24 elems each
    const long j = i - (1L << 24);
    const long seg = j >> 24;
    src = seg == 0 ? w_in : seg == 1 ? w1 : w2;
    loc = j & ((1L << 24) - 1);
  }
  const float4 f = *(const float4*)(src + loc);
  bf16x4 o;
  o[0] = (bf16)f.x; o[1] = (bf16)f.y; o[2] = (bf16)f.z; o[3] = (bf16)f.w;
  *(bf16x4*)(dst + i) = o;
}

extern "C" void kernel_launch(void* const* d_in, const int* in_sizes, int n_in,
                              void* d_out, int out_size, void* d_ws, size_t ws_size,
                              hipStream_t stream)
{
  const float* x      = (const float*)d_in[0];
  const float* wq     = (const float*)d_in[1];
  const float* bq     = (const float*)d_in[2];
  const float* wk     = (const float*)d_in[3];
  const float* bk     = (const float*)d_in[4];
  const float* wv     = (const float*)d_in[5];
  const float* bv     = (const float*)d_in[6];
  const float* wo     = (const float*)d_in[7];
  const float* bo     = (const float*)d_in[8];
  const float* scale1 = (const float*)d_in[9];
  const float* scale2 = (const float*)d_in[10];
  const float* w_in   = (const float*)d_in[11];
  const float* b_in   = (const float*)d_in[12];
  const float* w1     = (const float*)d_in[13];
  const float* b1     = (const float*)d_in[14];
  const float* w2     = (const float*)d_in[15];
  const float* b2     = (const float*)d_in[16];

  // ---- workspace layout (272 MiB total; ws is 288 MiB) ----
  // QKV (48 MB, dead after O-proj) aliases HID (64 MB, born after O-proj).
  char* ws = (char*)d_ws;
  bf16*  WB  = (bf16*)ws;                      // 134217728 B: bf16 weight pool
  float* R   = (float*)(ws + 134217728);       //  33554432 B: fp32 residual [4096,2048]
  bf16*  H   = (bf16*) (ws + 167772160);       //  16777216 B: bf16 normed acts
  bf16*  QKV = (bf16*) (ws + 184549376);       //  48 MB region (phase 1)
  bf16*  HID = (bf16*) (ws + 184549376);       //  64 MB region (phase 2, aliases QKV)
  float* G1  = (float*)(ws + 251658240);       //  33554432 B: fp32 [4096,2048]
  if (ws_size < 285212672ULL) { fprintf(stderr, "ws too small: %zu\n", ws_size); return; }

  bf16* wqkv_b = WB;                 // rows 0..6143 = wq|wk|wv  (contiguous)
  bf16* wo_b   = WB + 12582912;
  bf16* win_b  = WB + 16777216;
  bf16* w1_b   = WB + 33554432;
  bf16* w2_b   = WB + 50331648;

  convert_weights<<<65536, 256, 0, stream>>>(wq, wk, wv, wo, w_in, w1, w2, WB);
  // xr = x + rotary ; h1 = rmsnorm(xr, scale1)
  rms_rot<<<ROWS, 256, 0, stream>>>(x, scale1, R, H, 1);
  // fused QKV: [4096,6144]
  gemm_bt<5><<<dim3(48, 32), 256, 0, stream>>>(H, 2048, wqkv_b, 2048, bq, bk, bv,
                                               QKV, 6144, nullptr, nullptr);
  // per-position head attention; ctx -> Q slot of QKV
  attn_kernel<<<ROWS, 256, 0, stream>>>(QKV, QKV);
  // x2 = xr + ctx @ wo^T + bo   (in-place on R)
  gemm_bt<1><<<dim3(16, 32), 256, 0, stream>>>(QKV, 6144, wo_b, 2048, bo, nullptr, nullptr,
                                               R, 2048, R, nullptr);
  // h2 = rmsnorm(x2, scale2)
  rms_rot<<<ROWS, 256, 0, stream>>>(R, scale2, nullptr, H, 0);
  // hidden = h2 @ w_in^T + b_in  [4096,8192]
  gemm_bt<0><<<dim3(64, 32), 256, 0, stream>>>(H, 2048, win_b, 2048, b_in, nullptr, nullptr,
                                               HID, 8192, nullptr, nullptr);
  // g1 = hidden @ w1^T + b1
  gemm_bt<3><<<dim3(16, 32), 256, 0, stream>>>(HID, 8192, w1_b, 8192, b1, nullptr, nullptr,
                                               G1, 2048, nullptr, nullptr);
  // out = x2 + silu(g1) * (hidden @ w2^T + b2)
  gemm_bt<4><<<dim3(16, 32), 256, 0, stream>>>(HID, 8192, w2_b, 8192, b2, nullptr, nullptr,
                                               (float*)d_out, 2048, R, G1);
}

// Round 3
// 1137.640 us; speedup vs baseline: 1.0421x; 1.0421x over previous
//
#include <hip/hip_runtime.h>
#include <cstdio>
#include <cstdint>

typedef __bf16 bf16;
typedef __bf16 bf16x8 __attribute__((ext_vector_type(8)));
typedef __bf16 bf16x4 __attribute__((ext_vector_type(4)));
typedef float  f32x4  __attribute__((ext_vector_type(4)));

#define SEQ  2048
#define DIMM 2048
#define ROWS 4096   // B*S
#define EPSF 1e-5f

// ---- async global->LDS, 16B per lane (dest must be waveuniform + lane*16) ----
__device__ __forceinline__ void g2l16(const void* g, void* l) {
  __builtin_amdgcn_global_load_lds((__attribute__((address_space(1))) void*)g,
                                   (__attribute__((address_space(3))) void*)l,
                                   16, 0, 0);
}

// ============================================================================
// GEMM: C[M,N] = A[M,K] @ Bw[N,K]^T (+bias, + mode-specific epilogue)
// 128x128 tile, BK=32, 256 threads = 4 waves (2x2 of 64x64), 16x16x32 bf16 MFMA
// MODE 0: bf16 out = acc + bias0
// MODE 1: f32 out  = resid + acc + bias0          (in-place on resid allowed)
// MODE 3: f32 out  = acc + bias0
// MODE 5: bf16 out, tri-bias (QKV fused: col<2048 bq, <4096 bk, else bv)
// MODE 6: bf16 out, bi-bias  (W1W2 fused: col<2048 b1, else b2)
// ============================================================================
template<int MODE>
__global__ __launch_bounds__(256)
void gemm_bt(const bf16* __restrict__ A, int ldA,
             const bf16* __restrict__ Bw, int K,
             const float* __restrict__ bias0,
             const float* __restrict__ bias1,
             const float* __restrict__ bias2,
             void* Cout, int ldC,
             const float* resid)
{
  __shared__ bf16 sA[128 * 32];
  __shared__ bf16 sB[128 * 32];
  const int tid  = threadIdx.x;
  const int lane = tid & 63;
  const int wave = tid >> 6;
  const int wm = wave >> 1, wn = wave & 1;
  const long row0 = (long)blockIdx.y * 128;
  const long col0 = (long)blockIdx.x * 128;

  const bf16* Ab = A  + row0 * ldA;
  const bf16* Bb = Bw + col0 * (long)K;

  f32x4 acc[4][4] = {};

  // staging chunk ids: 512 x 16B chunks per tile, 2 per thread
  const int c0 = tid,        c1 = tid + 256;
  const int r0 = c0 >> 2,    cc0 = (c0 & 3) * 8;
  const int r1 = c1 >> 2,    cc1 = (c1 & 3) * 8;

  for (int k0 = 0; k0 < K; k0 += 32) {
    g2l16(Ab + (long)r0 * ldA + k0 + cc0, sA + c0 * 8);
    g2l16(Ab + (long)r1 * ldA + k0 + cc1, sA + c1 * 8);
    g2l16(Bb + (long)r0 * K   + k0 + cc0, sB + c0 * 8);
    g2l16(Bb + (long)r1 * K   + k0 + cc1, sB + c1 * 8);
    __syncthreads();   // also drains vmcnt for global_load_lds
    const int lm = lane & 15, lq = lane >> 4;
    bf16x8 af[4], bfr[4];
#pragma unroll
    for (int mi = 0; mi < 4; ++mi)
      af[mi] = *(const bf16x8*)(sA + (wm * 64 + mi * 16 + lm) * 32 + lq * 8);
#pragma unroll
    for (int ni = 0; ni < 4; ++ni)
      bfr[ni] = *(const bf16x8*)(sB + (wn * 64 + ni * 16 + lm) * 32 + lq * 8);
#pragma unroll
    for (int mi = 0; mi < 4; ++mi)
#pragma unroll
      for (int ni = 0; ni < 4; ++ni)
        acc[mi][ni] = __builtin_amdgcn_mfma_f32_16x16x32_bf16(af[mi], bfr[ni], acc[mi][ni], 0, 0, 0);
    __syncthreads();
  }

  // epilogue: C/D layout col=lane&15, row=(lane>>4)*4+reg  [m89/m91 verified]
  const int lm = lane & 15, lq = lane >> 4;
#pragma unroll
  for (int ni = 0; ni < 4; ++ni) {
    const long col = col0 + wn * 64 + ni * 16 + lm;
    float bv;
    if (MODE == 5)
      bv = (col < 2048) ? bias0[col] : (col < 4096 ? bias1[col - 2048] : bias2[col - 4096]);
    else if (MODE == 6)
      bv = (col < 2048) ? bias0[col] : bias1[col - 2048];
    else
      bv = bias0[col];
#pragma unroll
    for (int mi = 0; mi < 4; ++mi) {
#pragma unroll
      for (int r = 0; r < 4; ++r) {
        const long row = row0 + wm * 64 + mi * 16 + lq * 4 + r;
        const long idx = row * ldC + col;
        const float v = acc[mi][ni][r] + bv;
        if (MODE == 0 || MODE == 5 || MODE == 6) {
          ((bf16*)Cout)[idx] = (bf16)v;
        } else if (MODE == 1) {
          ((float*)Cout)[idx] = resid[idx] + v;
        } else { // MODE 3
          ((float*)Cout)[idx] = v;
        }
      }
    }
  }
}

// ============================================================================
// fused (optional additive-rotary) + RMSNorm: h = scale * x / sqrt(sum(x^2)+eps)
// one block per row; optionally writes fp32 x(+rot) residual
// ============================================================================
__global__ __launch_bounds__(256)
void rms_rot(const float* __restrict__ xin,
             const float* __restrict__ scale,
             float* __restrict__ xr_out,
             bf16* __restrict__ h_out,
             int do_rot)
{
  const int row = blockIdx.x, tid = threadIdx.x;
  const float s = (float)(row & (SEQ - 1));
  const float4* xrow = (const float4*)(xin + (long)row * DIMM);
  float4 v[2];
  float ss = 0.f;
#pragma unroll
  for (int i = 0; i < 2; ++i) {
    const int j4 = tid + i * 256;
    float4 xv = xrow[j4];
    if (do_rot) {
      float* xp = (float*)&xv;
#pragma unroll
      for (int l = 0; l < 4; ++l) {
        const int idx = (j4 * 4 + l) & 1023;   // table[j] = s * 10000^(-(j&1023)/1024)
        xp[l] += s * exp2f((float)idx * -0.0129762816206537569f); // -log2(1e4)/1024
      }
    }
    v[i] = xv;
    ss += xv.x * xv.x + xv.y * xv.y + xv.z * xv.z + xv.w * xv.w;
    if (xr_out) ((float4*)(xr_out + (long)row * DIMM))[j4] = xv;
  }
#pragma unroll
  for (int off = 32; off > 0; off >>= 1) ss += __shfl_down(ss, off, 64);
  __shared__ float red[4];
  if ((tid & 63) == 0) red[tid >> 6] = ss;
  __syncthreads();
  const float rn = rsqrtf(red[0] + red[1] + red[2] + red[3] + EPSF);
  bf16* hrow = h_out + (long)row * DIMM;
#pragma unroll
  for (int i = 0; i < 2; ++i) {
    const int j4 = tid + i * 256;
    const float4 xv = v[i];
    const float4 s4 = ((const float4*)scale)[j4];
    bf16x4 o;
    o[0] = (bf16)(s4.x * xv.x * rn);
    o[1] = (bf16)(s4.y * xv.y * rn);
    o[2] = (bf16)(s4.z * xv.z * rn);
    o[3] = (bf16)(s4.w * xv.w * rn);
    *(bf16x4*)(hrow + j4 * 4) = o;
  }
}

// ============================================================================
// per-position attention over HEADS (the reference's einsum): one block per
// token position. scores[q,k] = dot64(Qh[q],Kh[k])/8, softmax over k (32),
// ctx[q,:] = attn @ Vh. Reads QKV row [6144], writes ctx into the Q slot.
// LDS padded (stride 68 / 33) to avoid stride-64 bank conflicts.
// ============================================================================
__global__ __launch_bounds__(256)
void attn_kernel(const bf16* QKV, bf16* CTX)
{
  __shared__ float qs[32 * 68];
  __shared__ float ks[32 * 68];
  __shared__ float vs[2048];
  __shared__ float sc[32 * 33];
  const int p = blockIdx.x, tid = threadIdx.x;
  const bf16* base = QKV + (long)p * 6144;
  {
    const bf16x8 q8 = *(const bf16x8*)(base + tid * 8);
    const bf16x8 k8 = *(const bf16x8*)(base + 2048 + tid * 8);
    const bf16x8 v8 = *(const bf16x8*)(base + 4096 + tid * 8);
    const int hi = tid >> 3, d0 = (tid & 7) * 8;
#pragma unroll
    for (int l = 0; l < 8; ++l) {
      qs[hi * 68 + d0 + l] = (float)q8[l];
      ks[hi * 68 + d0 + l] = (float)k8[l];
      vs[hi * 64 + d0 + l] = (float)v8[l];
    }
  }
  __syncthreads();
  { // scores: thread -> row qi = tid>>3, cols ki = (tid&7) + 8c
    const int qi = tid >> 3, ku = tid & 7;
    float a[4] = {0.f, 0.f, 0.f, 0.f};
#pragma unroll
    for (int d = 0; d < 64; d += 4) {
      const float4 qv = *(const float4*)&qs[qi * 68 + d];
#pragma unroll
      for (int c = 0; c < 4; ++c) {
        const float4 kv = *(const float4*)&ks[(ku + 8 * c) * 68 + d];
        a[c] += qv.x * kv.x + qv.y * kv.y + qv.z * kv.z + qv.w * kv.w;
      }
    }
#pragma unroll
    for (int c = 0; c < 4; ++c) sc[qi * 33 + ku + 8 * c] = a[c] * 0.125f;
  }
  __syncthreads();
  if (tid < 32) { // softmax per q-row over 32 kv heads
    float mx = -1e30f;
#pragma unroll
    for (int k = 0; k < 32; ++k) mx = fmaxf(mx, sc[tid * 33 + k]);
    float e[32], sum = 0.f;
#pragma unroll
    for (int k = 0; k < 32; ++k) { e[k] = __expf(sc[tid * 33 + k] - mx); sum += e[k]; }
    const float inv = 1.f / sum;
#pragma unroll
    for (int k = 0; k < 32; ++k) sc[tid * 33 + k] = e[k] * inv;
  }
  __syncthreads();
  { // ctx: thread -> q = tid>>3, d = (tid&7)*8 .. +7 ; coalesced 16B store
    const int q = tid >> 3, d0 = (tid & 7) * 8;
    float a[8] = {};
#pragma unroll
    for (int k = 0; k < 32; ++k) {
      const float w = sc[q * 33 + k];
      const float4 v0 = *(const float4*)&vs[k * 64 + d0];
      const float4 v1 = *(const float4*)&vs[k * 64 + d0 + 4];
      a[0] += w * v0.x; a[1] += w * v0.y; a[2] += w * v0.z; a[3] += w * v0.w;
      a[4] += w * v1.x; a[5] += w * v1.y; a[6] += w * v1.z; a[7] += w * v1.w;
    }
    bf16x8 o;
#pragma unroll
    for (int l = 0; l < 8; ++l) o[l] = (bf16)a[l];
    *(bf16x8*)(CTX + (long)p * 6144 + tid * 8) = o;
  }
}

// ============================================================================
// swiglu combine: out = R + silu(g1) * g2,  g1 = G12[r, c], g2 = G12[r, c+2048]
// 8M outputs, 8 per thread, fully coalesced 16B accesses
// ============================================================================
__global__ __launch_bounds__(256)
void swiglu_combine(const bf16* __restrict__ G12, const float* __restrict__ R,
                    float* __restrict__ out)
{
  const long idx = ((long)blockIdx.x * 256 + threadIdx.x) * 8;  // output index
  const long row = idx >> 11, col = idx & 2047;
  const bf16x8 g1 = *(const bf16x8*)(G12 + row * 4096 + col);
  const bf16x8 g2 = *(const bf16x8*)(G12 + row * 4096 + 2048 + col);
  const float4 r0 = *(const float4*)(R + idx);
  const float4 r1 = *(const float4*)(R + idx + 4);
  float o[8];
  const float* rp0 = (const float*)&r0;
  const float* rp1 = (const float*)&r1;
#pragma unroll
  for (int l = 0; l < 8; ++l) {
    const float g  = (float)g1[l];
    const float si = g / (1.f + __expf(-g));
    const float rv = l < 4 ? rp0[l] : rp1[l - 4];
    o[l] = rv + si * (float)g2[l];
  }
  *(float4*)(out + idx)     = make_float4(o[0], o[1], o[2], o[3]);
  *(float4*)(out + idx + 4) = make_float4(o[4], o[5], o[6], o[7]);
}

// ============================================================================
// fp32 -> bf16 weight pool: [wq|wk|wv|wo|w_in|w1|w2]  (67,108,864 elements)
// ============================================================================
__global__ __launch_bounds__(256)
void convert_weights(const float* __restrict__ wq, const float* __restrict__ wk,
                     const float* __restrict__ wv, const float* __restrict__ wo,
                     const float* __restrict__ w_in, const float* __restrict__ w1,
                     const float* __restrict__ w2, bf16* __restrict__ dst)
{
  const long i = ((long)blockIdx.x * 256 + threadIdx.x) * 4;
  const float* src; long loc;
  if (i < (1L << 24)) {                 // 4 attn weights, 2^22 elems each
    const long seg = i >> 22;
    src = seg == 0 ? wq : seg == 1 ? wk : seg == 2 ? wv : wo;
    loc = i & ((1L << 22) - 1);
  } else {                              // 3 mlp weights, 2^24 elems each
    const long j = i - (1L << 24);
    const long seg = j >> 24;
    src = seg == 0 ? w_in : seg == 1 ? w1 : w2;
    loc = j & ((1L << 24) - 1);
  }
  const float4 f = *(const float4*)(src + loc);
  bf16x4 o;
  o[0] = (bf16)f.x; o[1] = (bf16)f.y; o[2] = (bf16)f.z; o[3] = (bf16)f.w;
  *(bf16x4*)(dst + i) = o;
}

extern "C" void kernel_launch(void* const* d_in, const int* in_sizes, int n_in,
                              void* d_out, int out_size, void* d_ws, size_t ws_size,
                              hipStream_t stream)
{
  const float* x      = (const float*)d_in[0];
  const float* wq     = (const float*)d_in[1];
  const float* bq     = (const float*)d_in[2];
  const float* wk     = (const float*)d_in[3];
  const float* bk     = (const float*)d_in[4];
  const float* wv     = (const float*)d_in[5];
  const float* bv     = (const float*)d_in[6];
  const float* wo     = (const float*)d_in[7];
  const float* bo     = (const float*)d_in[8];
  const float* scale1 = (const float*)d_in[9];
  const float* scale2 = (const float*)d_in[10];
  const float* w_in   = (const float*)d_in[11];
  const float* b_in   = (const float*)d_in[12];
  const float* w1     = (const float*)d_in[13];
  const float* b1     = (const float*)d_in[14];
  const float* w2     = (const float*)d_in[15];
  const float* b2     = (const float*)d_in[16];

  // ---- workspace layout (272 MiB total; ws is 288 MiB) ----
  // QKV (48 MB, dead after O-proj) aliases HID (64 MB, born after O-proj).
  char* ws = (char*)d_ws;
  bf16*  WB  = (bf16*)ws;                      // 134217728 B: bf16 weight pool
  float* R   = (float*)(ws + 134217728);       //  33554432 B: fp32 residual [4096,2048]
  bf16*  H   = (bf16*) (ws + 167772160);       //  16777216 B: bf16 normed acts
  bf16*  QKV = (bf16*) (ws + 184549376);       //  48 MB region (phase 1)
  bf16*  HID = (bf16*) (ws + 184549376);       //  64 MB region (phase 2, aliases QKV)
  bf16*  G12 = (bf16*) (ws + 251658240);       //  33554432 B: bf16 [4096,4096] g1|g2
  if (ws_size < 285212672ULL) { fprintf(stderr, "ws too small: %zu\n", ws_size); return; }

  bf16* wqkv_b = WB;                 // rows 0..6143 = wq|wk|wv  (contiguous)
  bf16* wo_b   = WB + 12582912;
  bf16* win_b  = WB + 16777216;
  bf16* w12_b  = WB + 33554432;      // rows 0..4095 = w1|w2   (contiguous)

  convert_weights<<<65536, 256, 0, stream>>>(wq, wk, wv, wo, w_in, w1, w2, WB);
  // xr = x + rotary ; h1 = rmsnorm(xr, scale1)
  rms_rot<<<ROWS, 256, 0, stream>>>(x, scale1, R, H, 1);
  // fused QKV: [4096,6144]
  gemm_bt<5><<<dim3(48, 32), 256, 0, stream>>>(H, 2048, wqkv_b, 2048, bq, bk, bv,
                                               QKV, 6144, nullptr);
  // per-position head attention; ctx -> Q slot of QKV
  attn_kernel<<<ROWS, 256, 0, stream>>>(QKV, QKV);
  // x2 = xr + ctx @ wo^T + bo   (in-place on R)
  gemm_bt<1><<<dim3(16, 32), 256, 0, stream>>>(QKV, 6144, wo_b, 2048, bo, nullptr, nullptr,
                                               R, 2048, R);
  // h2 = rmsnorm(x2, scale2)
  rms_rot<<<ROWS, 256, 0, stream>>>(R, scale2, nullptr, H, 0);
  // hidden = h2 @ w_in^T + b_in  [4096,8192]
  gemm_bt<0><<<dim3(64, 32), 256, 0, stream>>>(H, 2048, win_b, 2048, b_in, nullptr, nullptr,
                                               HID, 8192, nullptr);
  // fused g1|g2 = hidden @ [w1|w2]^T + [b1|b2]  -> bf16 [4096,4096]
  gemm_bt<6><<<dim3(32, 32), 256, 0, stream>>>(HID, 8192, w12_b, 8192, b1, b2, nullptr,
                                               G12, 4096, nullptr);
  // out = x2 + silu(g1) * g2
  swiglu_combine<<<4096, 256, 0, stream>>>(G12, R, (float*)d_out);
}